// Round 7
// baseline (361.522 us; speedup 1.0000x reference)
//
#include <hip/hip_runtime.h>

// Fused attention: B=8, S=2048, D=512, fp32 in/out, bf16 MFMA compute.
// cvt(fp32->bf16) -> qkv_gemm (Q,K row-major; V blocked panels
// Vtb[b][t32][512][32]) -> flash attn (8-wave QBLK=128, KVBLK=64, Ksm double
// buffered + counted vmcnt, V-frags direct from global panels, 2-way split-K)
// -> combine.

typedef unsigned short u16;
typedef unsigned int u32;
typedef u16 u16x4 __attribute__((ext_vector_type(4)));
typedef float f32x4 __attribute__((ext_vector_type(4)));
typedef __bf16 bf16x8 __attribute__((ext_vector_type(8)));

#define NBATCH 8
#define NS 2048
#define ND 512
#define NM (NBATCH*NS)  // 16384 tokens

typedef __attribute__((address_space(1))) u32 gu32;
typedef __attribute__((address_space(3))) u32 lu32;
#define GLD16(g, l) __builtin_amdgcn_global_load_lds((gu32*)(g), (lu32*)(l), 16, 0, 0)

__device__ __forceinline__ u16 f2bf(float f) {  // RNE fp32->bf16
  union { float f; u32 u; } v; v.f = f;
  u32 r = v.u + 0x7FFFu + ((v.u >> 16) & 1u);
  return (u16)(r >> 16);
}

__device__ __forceinline__ f32x4 mfma16(bf16x8 a, bf16x8 b, f32x4 c) {
  return __builtin_amdgcn_mfma_f32_16x16x32_bf16(a, b, c, 0, 0, 0);
}

// ---------------- fp32 -> bf16 convert --------------------------------------
__global__ void cvt_kernel(const float* __restrict__ batch,
                           const float* __restrict__ wq,
                           const float* __restrict__ wk,
                           const float* __restrict__ wv,
                           u16* __restrict__ Xb, u16* __restrict__ Wqb,
                           u16* __restrict__ Wkb, u16* __restrict__ Wvb) {
  const int MD4 = NM * ND / 4;
  const int W4 = ND * ND / 4;
  int total = MD4 + 3 * W4;
  for (int i = blockIdx.x * blockDim.x + threadIdx.x; i < total;
       i += gridDim.x * blockDim.x) {
    const float4* src; u16x4* dst; int off;
    if (i < MD4)             { src = (const float4*)batch; dst = (u16x4*)Xb;  off = i; }
    else if (i < MD4 + W4)   { src = (const float4*)wq;    dst = (u16x4*)Wqb; off = i - MD4; }
    else if (i < MD4 + 2*W4) { src = (const float4*)wk;    dst = (u16x4*)Wkb; off = i - MD4 - W4; }
    else                     { src = (const float4*)wv;    dst = (u16x4*)Wvb; off = i - MD4 - 2*W4; }
    float4 v = src[off];
    u16x4 o; o[0] = f2bf(v.x); o[1] = f2bf(v.y); o[2] = f2bf(v.z); o[3] = f2bf(v.w);
    dst[off] = o;
  }
}

// ---------------- QKV projection GEMM ---------------------------------------
// z=0: Q (+bias, *1/sqrt(D)); z=1: K; z=2: V into blocked panels
// Vtb[b][t=s/32][d][s%32] so a D x 32 key-panel is 32KB contiguous.
__global__ __launch_bounds__(256) void qkv_gemm(
    const u16* __restrict__ Xb,
    const u16* __restrict__ Wqb, const u16* __restrict__ Wkb, const u16* __restrict__ Wvb,
    const float* __restrict__ bq, const float* __restrict__ bk, const float* __restrict__ bv,
    u16* __restrict__ Qb, u16* __restrict__ Kb, u16* __restrict__ Vtb) {
  __shared__ u16 Asm[128 * 64];
  __shared__ u16 Bsm[128 * 64];
  int tid = threadIdx.x;
  int w = tid >> 6, lane = tid & 63, la = lane & 15, hi = lane >> 4;
  int wm = w >> 1, wn = w & 1;
  int m0 = blockIdx.x * 128, n0 = blockIdx.y * 128, z = blockIdx.z;
  const u16* W = (z == 0) ? Wqb : (z == 1) ? Wkb : Wvb;
  f32x4 acc[4][4];
  f32x4 zero = {0.f, 0.f, 0.f, 0.f};
#pragma unroll
  for (int mi = 0; mi < 4; ++mi)
#pragma unroll
    for (int ni = 0; ni < 4; ++ni) acc[mi][ni] = zero;

  for (int kt = 0; kt < 8; ++kt) {
#pragma unroll
    for (int i = 0; i < 4; ++i) {
      int c = w * 4 + i;
      int row = c * 8 + (lane >> 3);
      const char* ga = (const char*)Xb + ((size_t)(m0 + row) * ND + kt * 64) * 2 + (lane & 7) * 16;
      GLD16(ga, (char*)Asm + c * 1024);
      const char* gb = (const char*)W + ((size_t)(n0 + row) * ND + kt * 64) * 2 + (lane & 7) * 16;
      GLD16(gb, (char*)Bsm + c * 1024);
    }
    __syncthreads();
#pragma unroll
    for (int kk = 0; kk < 2; ++kk) {
      bf16x8 a[4], bfr[4];
#pragma unroll
      for (int mi = 0; mi < 4; ++mi)
        a[mi] = *(const bf16x8*)((const char*)Asm + (wm * 64 + mi * 16 + la) * 128 + kk * 64 + hi * 16);
#pragma unroll
      for (int ni = 0; ni < 4; ++ni)
        bfr[ni] = *(const bf16x8*)((const char*)Bsm + (wn * 64 + ni * 16 + la) * 128 + kk * 64 + hi * 16);
#pragma unroll
      for (int mi = 0; mi < 4; ++mi)
#pragma unroll
        for (int ni = 0; ni < 4; ++ni)
          acc[mi][ni] = mfma16(a[mi], bfr[ni], acc[mi][ni]);
    }
    __syncthreads();
  }

  const float* bias = (z == 0) ? bq : (z == 1) ? bk : bv;
  float scl = (z == 0) ? 0.044194173824159216f : 1.0f;  // 1/sqrt(512) folded into Q
#pragma unroll
  for (int mi = 0; mi < 4; ++mi) {
#pragma unroll
    for (int ni = 0; ni < 4; ++ni) {
      int col = n0 + wn * 64 + ni * 16 + la;
      int rbase = m0 + wm * 64 + mi * 16 + hi * 4;    // token row, %4==0
      float bc = bias[col];
      if (z == 2) {
        int bbx = rbase >> 11;
        int tt = (rbase & 2047) >> 5;                 // 32-key panel index
        int kk2 = rbase & 31;                         // pos in panel (4-aligned)
        u16x4 pk;
#pragma unroll
        for (int j = 0; j < 4; ++j) pk[j] = f2bf(acc[mi][ni][j] + bc);
        *(u16x4*)((char*)Vtb + (((size_t)(bbx * 64 + tt) * 512 + col) * 32 + kk2) * 2) = pk;
      } else {
        u16* Ob = (z == 0) ? Qb : Kb;
#pragma unroll
        for (int j = 0; j < 4; ++j)
          Ob[(size_t)(rbase + j) * ND + col] = f2bf((acc[mi][ni][j] + bc) * scl);
      }
    }
  }
}

// ---------------- flash attention (8 waves, QBLK=128, Ksm dbuf) -------------
// 256 blocks, 1/CU: b=bi&7 (XCD pin); bi<128: qt=(bi>>3)&15,c=0; else
// qt=15-((bi>>3)&15),c=1. Chunk = qt+1 64-key tiles (<=16). QK: wave w owns
// q-rows q0+w*16..+16 (swapped MFMA, lane la = q-row). PV: wave owns
// q-half (w>>2)*64 x d-slice (w&3)*128. Ksm double-buffered; per tile:
// barrier -> QK(buf) -> STAGE_K(t+1, buf^1) -> softmax -> P publish ->
// lgkmcnt0+barrier -> rescale+PV -> LOAD_VF(t+1) -> vmcnt(16) -> loop.
__global__ __launch_bounds__(512) void attn_kernel(
    const u16* __restrict__ Qb, const u16* __restrict__ Kb, const u16* __restrict__ Vtb,
    const int* __restrict__ lens,
    u16* __restrict__ pOh, float* __restrict__ pM, float* __restrict__ pL) {
  __shared__ u16 Ksm[2][64 * 512];  // 2 x 64 KB
  __shared__ u16 Psm[128 * 72];     // 18 KB, row stride 144 B
  __shared__ float Alds[128];

  int bi = blockIdx.x;
  int b = bi & 7;
  int h = bi >> 7;
  int q8 = (bi >> 3) & 15;
  int qt = h ? (15 - q8) : q8;
  int c = h;
  int len = lens[b];
  int q0 = qt * 128;
  int kmax = min(q0 + 127, len - 1);
  int lastT = kmax >> 6;          // 64-key tiles, 0..31
  int half = qt + 1;              // chunk size at full length
  int t0 = c * half;
  int t1 = min(lastT + 1, t0 + half);
  int slot = (b * 16 + qt) * 2 + c;
  int tid = threadIdx.x;
  int w = tid >> 6, lane = tid & 63, la = lane & 15, hi = lane >> 4;

  if (t0 >= t1) {                 // empty chunk (short length)
    if (tid < 128) { pM[slot * 128 + tid] = -1e30f; pL[slot * 128 + tid] = 0.f; }
    return;
  }

  int r0 = q0 + w * 16;
  int qrow = r0 + la;             // q-row this lane owns in S^T domain
  int qh = w >> 2, ds = (w & 3) * 128;  // PV role

  // Q fragments (resident whole kernel): 64 VGPR
  bf16x8 qf[16];
  const char* qbase = (const char*)Qb + (size_t)(b * NS + r0 + la) * ND * 2 + hi * 16;
#pragma unroll
  for (int kc = 0; kc < 16; ++kc) qf[kc] = *(const bf16x8*)(qbase + kc * 64);

  f32x4 o[4][8];                  // O[q = qh*64+qb*16+hi*4+j][d = ds+nb*16+la]
  f32x4 zero = {0.f, 0.f, 0.f, 0.f};
#pragma unroll
  for (int qb = 0; qb < 4; ++qb)
#pragma unroll
    for (int nb = 0; nb < 8; ++nb) o[qb][nb] = zero;
  float mrow = -1e30f, lrow = 0.f;

#define STAGE_K(T) {                                                            \
  _Pragma("unroll")                                                             \
  for (int i_ = 0; i_ < 8; ++i_) {                                              \
    int r_ = w * 8 + i_;                                                        \
    const char* g_ = (const char*)Kb + (size_t)(b * NS + (T) * 64 + r_) * ND * 2 \
                     + ((lane ^ (r_ & 7)) * 16);                                \
    GLD16(g_, (char*)Ksm[(T) & 1] + r_ * 1024);                                 \
  } }
#define LOAD_VF(T) {                                                            \
  _Pragma("unroll")                                                             \
  for (int ks_ = 0; ks_ < 2; ++ks_) {                                           \
    const char* pan_ = (const char*)Vtb + ((size_t)(b * 64 + 2 * (T) + ks_) * 512) * 64; \
    _Pragma("unroll")                                                           \
    for (int nb_ = 0; nb_ < 8; ++nb_) {                                         \
      int d_ = ds + nb_ * 16 + la;                                              \
      vf[ks_][nb_] = *(const bf16x8*)(pan_ + d_ * 64 + hi * 16);                \
    }                                                                           \
  } }

  bf16x8 vf[2][8];
  STAGE_K(t0);
  LOAD_VF(t0);
  // qf(16) + K(8) retired; vf(16) may still fly (compiler waits before PV use)
  asm volatile("s_waitcnt vmcnt(16)" ::: "memory");
  __builtin_amdgcn_s_barrier();

  for (int t = t0; t < t1; ++t) {
    int k0 = t * 64;
    bool more = (t + 1 < t1);
    const char* kbase = (const char*)Ksm[t & 1];

    // QK^T (swapped): s[f] rows = keys f*16+hi*4+j, col = q-row la
    f32x4 s[4];
#pragma unroll
    for (int f = 0; f < 4; ++f) s[f] = zero;
#pragma unroll
    for (int kc = 0; kc < 16; ++kc) {
#pragma unroll
      for (int f = 0; f < 4; ++f) {
        int row = f * 16 + la;
        const char* p = kbase + row * 1024 + ((kc * 64 + hi * 16) ^ ((row & 7) * 16));
        bf16x8 kf = *(const bf16x8*)p;
        s[f] = mfma16(kf, qf[kc], s[f]);
      }
    }

    if (more) STAGE_K(t + 1);     // into buf^1 (no one reads it: dbuf)

    // mask + online softmax (per q-row = lane la, replicated across hi)
    float tmax = -1e30f;
#pragma unroll
    for (int f = 0; f < 4; ++f) {
#pragma unroll
      for (int j = 0; j < 4; ++j) {
        int kabs = k0 + f * 16 + hi * 4 + j;
        bool ok = (kabs <= qrow) && (kabs < len);
        float vv = ok ? s[f][j] : -1e30f;
        s[f][j] = vv;
        tmax = fmaxf(tmax, vv);
      }
    }
    tmax = fmaxf(tmax, __shfl_xor(tmax, 16));
    tmax = fmaxf(tmax, __shfl_xor(tmax, 32));
    float mnew = fmaxf(fmaxf(mrow, tmax), -1e20f);  // floor: all-masked rows keep l=0
    float alpha = __expf(mrow - mnew);
    float psum = 0.f;
#pragma unroll
    for (int f = 0; f < 4; ++f) {
#pragma unroll
      for (int j = 0; j < 4; ++j) {
        float p = __expf(s[f][j] - mnew);
        s[f][j] = p;
        psum += p;
      }
    }
    psum += __shfl_xor(psum, 16);
    psum += __shfl_xor(psum, 32);
    lrow = lrow * alpha + psum;
    mrow = mnew;

    // publish P (bf16) + alpha
#pragma unroll
    for (int f = 0; f < 4; ++f) {
      u16x4 pk;
#pragma unroll
      for (int j = 0; j < 4; ++j) pk[j] = f2bf(s[f][j]);
      *(u16x4*)((char*)Psm + (w * 16 + la) * 144 + (f * 16 + hi * 4) * 2) = pk;
    }
    if (hi == 0) Alds[w * 16 + la] = alpha;
    asm volatile("s_waitcnt lgkmcnt(0)" ::: "memory");
    __builtin_amdgcn_s_barrier();          // P/Alds visible; Ksm(buf) reads done

    // rescale O by alpha (per O-row q = qh*64+qb*16+hi*4+j)
    float aq[4][4];
#pragma unroll
    for (int qb = 0; qb < 4; ++qb)
#pragma unroll
      for (int j = 0; j < 4; ++j) aq[qb][j] = Alds[qh * 64 + qb * 16 + hi * 4 + j];
#pragma unroll
    for (int qb = 0; qb < 4; ++qb)
#pragma unroll
      for (int nb = 0; nb < 8; ++nb) {
        o[qb][nb][0] *= aq[qb][0]; o[qb][nb][1] *= aq[qb][1];
        o[qb][nb][2] *= aq[qb][2]; o[qb][nb][3] *= aq[qb][3];
      }

    // PV: wave owns q-half qh, d-slice ds (vf(t) waited by compiler)
#pragma unroll
    for (int ks = 0; ks < 2; ++ks) {
#pragma unroll
      for (int qb = 0; qb < 4; ++qb) {
        bf16x8 pf = *(const bf16x8*)((const char*)Psm + (qh * 64 + qb * 16 + la) * 144 + ks * 64 + hi * 16);
#pragma unroll
        for (int nb = 0; nb < 8; ++nb) o[qb][nb] = mfma16(pf, vf[ks][nb], o[qb][nb]);
      }
    }

    if (more) {
      LOAD_VF(t + 1);                                   // vf regs for t+1
      asm volatile("s_waitcnt vmcnt(16)" ::: "memory"); // K(t+1) landed; vf flying
      __builtin_amdgcn_s_barrier();                     // Ksm(buf^1) ready; Psm reads done
    }
  }

  // epilogue: bf16 partials + m/l
  if (hi == 0) { pM[slot * 128 + w * 16 + la] = mrow; pL[slot * 128 + w * 16 + la] = lrow; }
  u16* dst = pOh + (size_t)slot * (128 * 512);
#pragma unroll
  for (int qb = 0; qb < 4; ++qb)
#pragma unroll
    for (int nb = 0; nb < 8; ++nb) {
      int base = (qh * 64 + qb * 16 + hi * 4) * 512 + ds + nb * 16 + la;
#pragma unroll
      for (int j = 0; j < 4; ++j) dst[base + j * 512] = f2bf(o[qb][nb][j]);
    }
#undef STAGE_K
#undef LOAD_VF
}

// ---------------- combine the 2 chunks per (b, qt) --------------------------
__global__ __launch_bounds__(256) void combine_kernel(
    const u16* __restrict__ pOh, const float* __restrict__ pM,
    const float* __restrict__ pL, float* __restrict__ out) {
  int qt = blockIdx.x, b = blockIdx.y;
  int s0 = (b * 16 + qt) * 2;
  int tid = threadIdx.x;
  int row = tid >> 1, dh = tid & 1;   // row 0..127, d-half (256 each)
  float m0 = pM[s0 * 128 + row], m1 = pM[(s0 + 1) * 128 + row];
  float l0 = pL[s0 * 128 + row], l1 = pL[(s0 + 1) * 128 + row];
  float m = fmaxf(m0, m1);
  float a0 = __expf(m0 - m), a1 = __expf(m1 - m);
  float linv = 1.0f / (l0 * a0 + l1 * a1);   // l0 > 0 always (key 0 unmasked)
  float c0 = a0 * linv, c1 = a1 * linv;
  bool has1 = (l1 > 0.f);
  const uint4* O0 = (const uint4*)(pOh + (size_t)s0 * 65536) + row * 64 + dh * 32;
  const uint4* O1 = (const uint4*)(pOh + (size_t)(s0 + 1) * 65536) + row * 64 + dh * 32;
  float4* Op = (float4*)(out + ((size_t)b * NS + qt * 128 + row) * ND) + dh * 64;
#pragma unroll 4
  for (int k = 0; k < 32; ++k) {
    uint4 v0 = O0[k];
    uint4 v1 = has1 ? O1[k] : uint4{0, 0, 0, 0};
    u32 w0[4] = {v0.x, v0.y, v0.z, v0.w};
    u32 w1[4] = {v1.x, v1.y, v1.z, v1.w};
    float4 r[2];
#pragma unroll
    for (int p = 0; p < 4; ++p) {
      float f0lo = __uint_as_float(w0[p] << 16), f0hi = __uint_as_float(w0[p] & 0xFFFF0000u);
      float f1lo = __uint_as_float(w1[p] << 16), f1hi = __uint_as_float(w1[p] & 0xFFFF0000u);
      ((float*)r)[p * 2]     = f0lo * c0 + f1lo * c1;
      ((float*)r)[p * 2 + 1] = f0hi * c0 + f1hi * c1;
    }
    Op[k * 2] = r[0];
    Op[k * 2 + 1] = r[1];
  }
}

extern "C" void kernel_launch(void* const* d_in, const int* in_sizes, int n_in,
                              void* d_out, int out_size, void* d_ws, size_t ws_size,
                              hipStream_t stream) {
  const float* batch = (const float*)d_in[0];
  const float* wq = (const float*)d_in[1];
  const float* bq = (const float*)d_in[2];
  const float* wk = (const float*)d_in[3];
  const float* bk = (const float*)d_in[4];
  const float* wv = (const float*)d_in[5];
  const float* bv = (const float*)d_in[6];
  const int* lens = (const int*)d_in[7];

  char* ws = (char*)d_ws;
  // Q/K/Vtb live through attn. Xb/W* dead after gemm -> pOh aliases them.
  u16* Qb   = (u16*)(ws + 0);          // 16 MB
  u16* Kb   = (u16*)(ws + 16777216);   // 16 MB
  u16* Vtb  = (u16*)(ws + 33554432);   // 16 MB  [B][64][512][32] panels
  u16* Xb   = (u16*)(ws + 50331648);   // 16 MB  (dead after gemm)
  u16* Wqb  = (u16*)(ws + 67108864);   // 512 KB (dead after gemm)
  u16* Wkb  = (u16*)(ws + 67633152);   // 512 KB
  u16* Wvb  = (u16*)(ws + 68157440);   // 512 KB
  u16* pOh  = (u16*)(ws + 50331648);   // 32 MB: 256 slots x 128x512 bf16 (aliases Xb/W*)
  float* pM = (float*)(ws + 83886080);  // 128 KB (256 x 128 f32)
  float* pL = (float*)(ws + 84017152);  // 128 KB; total ws use ~84.1 MB

  cvt_kernel<<<dim3(2048), dim3(256), 0, stream>>>(batch, wq, wk, wv, Xb, Wqb, Wkb, Wvb);
  qkv_gemm<<<dim3(128, 4, 3), dim3(256), 0, stream>>>(Xb, Wqb, Wkb, Wvb, bq, bk, bv, Qb, Kb, Vtb);
  attn_kernel<<<dim3(256), dim3(512), 0, stream>>>(Qb, Kb, Vtb, lens, pOh, pM, pL);
  combine_kernel<<<dim3(16, 8), dim3(256), 0, stream>>>(pOh, pM, pL, (float*)d_out);
}

// Round 8
// 201.079 us; speedup vs baseline: 1.7979x; 1.7979x over previous
//
#include <hip/hip_runtime.h>

// Fused attention: B=8, S=2048, D=512, fp32 in/out, bf16 MFMA compute.
// cvt(fp32->bf16) -> qkv_gemm (Q,K row-major; V blocked panels
// Vtb[b][t32][512][32]) -> flash attn (QBLK=64/4 waves, KVBLK=32, Ksm TRUE
// double-buffer, counted vmcnt only, V-frags reg-direct from panels, 2-way
// balanced split-K, 2 blocks/CU) -> combine.

typedef unsigned short u16;
typedef unsigned int u32;
typedef u16 u16x4 __attribute__((ext_vector_type(4)));
typedef float f32x4 __attribute__((ext_vector_type(4)));
typedef __bf16 bf16x8 __attribute__((ext_vector_type(8)));

#define NBATCH 8
#define NS 2048
#define ND 512
#define NM (NBATCH*NS)  // 16384 tokens

typedef __attribute__((address_space(1))) u32 gu32;
typedef __attribute__((address_space(3))) u32 lu32;
#define GLD16(g, l) __builtin_amdgcn_global_load_lds((gu32*)(g), (lu32*)(l), 16, 0, 0)

__device__ __forceinline__ u16 f2bf(float f) {  // RNE fp32->bf16
  union { float f; u32 u; } v; v.f = f;
  u32 r = v.u + 0x7FFFu + ((v.u >> 16) & 1u);
  return (u16)(r >> 16);
}

__device__ __forceinline__ f32x4 mfma16(bf16x8 a, bf16x8 b, f32x4 c) {
  return __builtin_amdgcn_mfma_f32_16x16x32_bf16(a, b, c, 0, 0, 0);
}

// ---------------- fp32 -> bf16 convert --------------------------------------
__global__ void cvt_kernel(const float* __restrict__ batch,
                           const float* __restrict__ wq,
                           const float* __restrict__ wk,
                           const float* __restrict__ wv,
                           u16* __restrict__ Xb, u16* __restrict__ Wqb,
                           u16* __restrict__ Wkb, u16* __restrict__ Wvb) {
  const int MD4 = NM * ND / 4;
  const int W4 = ND * ND / 4;
  int total = MD4 + 3 * W4;
  for (int i = blockIdx.x * blockDim.x + threadIdx.x; i < total;
       i += gridDim.x * blockDim.x) {
    const float4* src; u16x4* dst; int off;
    if (i < MD4)             { src = (const float4*)batch; dst = (u16x4*)Xb;  off = i; }
    else if (i < MD4 + W4)   { src = (const float4*)wq;    dst = (u16x4*)Wqb; off = i - MD4; }
    else if (i < MD4 + 2*W4) { src = (const float4*)wk;    dst = (u16x4*)Wkb; off = i - MD4 - W4; }
    else                     { src = (const float4*)wv;    dst = (u16x4*)Wvb; off = i - MD4 - 2*W4; }
    float4 v = src[off];
    u16x4 o; o[0] = f2bf(v.x); o[1] = f2bf(v.y); o[2] = f2bf(v.z); o[3] = f2bf(v.w);
    dst[off] = o;
  }
}

// ---------------- QKV projection GEMM ---------------------------------------
// z=0: Q (+bias, *1/sqrt(D)); z=1: K; z=2: V into blocked panels
// Vtb[b][t=s/32][d][s%32] so a D x 32 key-panel is 32KB contiguous.
__global__ __launch_bounds__(256) void qkv_gemm(
    const u16* __restrict__ Xb,
    const u16* __restrict__ Wqb, const u16* __restrict__ Wkb, const u16* __restrict__ Wvb,
    const float* __restrict__ bq, const float* __restrict__ bk, const float* __restrict__ bv,
    u16* __restrict__ Qb, u16* __restrict__ Kb, u16* __restrict__ Vtb) {
  __shared__ u16 Asm[128 * 64];
  __shared__ u16 Bsm[128 * 64];
  int tid = threadIdx.x;
  int w = tid >> 6, lane = tid & 63, la = lane & 15, hi = lane >> 4;
  int wm = w >> 1, wn = w & 1;
  int m0 = blockIdx.x * 128, n0 = blockIdx.y * 128, z = blockIdx.z;
  const u16* W = (z == 0) ? Wqb : (z == 1) ? Wkb : Wvb;
  f32x4 acc[4][4];
  f32x4 zero = {0.f, 0.f, 0.f, 0.f};
#pragma unroll
  for (int mi = 0; mi < 4; ++mi)
#pragma unroll
    for (int ni = 0; ni < 4; ++ni) acc[mi][ni] = zero;

  for (int kt = 0; kt < 8; ++kt) {
#pragma unroll
    for (int i = 0; i < 4; ++i) {
      int c = w * 4 + i;
      int row = c * 8 + (lane >> 3);
      const char* ga = (const char*)Xb + ((size_t)(m0 + row) * ND + kt * 64) * 2 + (lane & 7) * 16;
      GLD16(ga, (char*)Asm + c * 1024);
      const char* gb = (const char*)W + ((size_t)(n0 + row) * ND + kt * 64) * 2 + (lane & 7) * 16;
      GLD16(gb, (char*)Bsm + c * 1024);
    }
    __syncthreads();
#pragma unroll
    for (int kk = 0; kk < 2; ++kk) {
      bf16x8 a[4], bfr[4];
#pragma unroll
      for (int mi = 0; mi < 4; ++mi)
        a[mi] = *(const bf16x8*)((const char*)Asm + (wm * 64 + mi * 16 + la) * 128 + kk * 64 + hi * 16);
#pragma unroll
      for (int ni = 0; ni < 4; ++ni)
        bfr[ni] = *(const bf16x8*)((const char*)Bsm + (wn * 64 + ni * 16 + la) * 128 + kk * 64 + hi * 16);
#pragma unroll
      for (int mi = 0; mi < 4; ++mi)
#pragma unroll
        for (int ni = 0; ni < 4; ++ni)
          acc[mi][ni] = mfma16(a[mi], bfr[ni], acc[mi][ni]);
    }
    __syncthreads();
  }

  const float* bias = (z == 0) ? bq : (z == 1) ? bk : bv;
  float scl = (z == 0) ? 0.044194173824159216f : 1.0f;  // 1/sqrt(512) folded into Q
#pragma unroll
  for (int mi = 0; mi < 4; ++mi) {
#pragma unroll
    for (int ni = 0; ni < 4; ++ni) {
      int col = n0 + wn * 64 + ni * 16 + la;
      int rbase = m0 + wm * 64 + mi * 16 + hi * 4;    // token row, %4==0
      float bc = bias[col];
      if (z == 2) {
        int bbx = rbase >> 11;
        int tt = (rbase & 2047) >> 5;                 // 32-key panel index
        int kk2 = rbase & 31;                         // pos in panel (4-aligned)
        u16x4 pk;
#pragma unroll
        for (int j = 0; j < 4; ++j) pk[j] = f2bf(acc[mi][ni][j] + bc);
        *(u16x4*)((char*)Vtb + (((size_t)(bbx * 64 + tt) * 512 + col) * 32 + kk2) * 2) = pk;
      } else {
        u16* Ob = (z == 0) ? Qb : Kb;
#pragma unroll
        for (int j = 0; j < 4; ++j)
          Ob[(size_t)(rbase + j) * ND + col] = f2bf((acc[mi][ni][j] + bc) * scl);
      }
    }
  }
}

// ---------------- flash attention (KVBLK=32, Ksm dbuf, drain-free) ----------
// 512 blocks: b=bi&7 (XCD pin); bi<256: qt=(bi>>3)&31,c=0; else
// qt=31-((bi>>3)&31),c=1. Chunks are exactly qt+1 32-key tiles each (full
// length), so the CU pair (bi,bi+256) sums to 33 tiles. Per tile t:
//   top:  if(more) STAGE_K(t+1 -> buf^1)        [8 GLD16/wave]
//   QK(buf) -> softmax -> P publish -> lgkmcnt0
//   vmcnt(8|0)  [vf(t) landed; K(t+1) still flying] -> barrier
//   rescale -> PV (Psm x vf regs)
//   if(more) LOAD_VF(t+1) -> vmcnt(8) [K(t+1) landed; vf(t+1) flying] -> barrier
// No vmcnt(0) mid-loop; no read-drain before any barrier.
__global__ __launch_bounds__(256) void attn_kernel(
    const u16* __restrict__ Qb, const u16* __restrict__ Kb, const u16* __restrict__ Vtb,
    const int* __restrict__ lens,
    u16* __restrict__ pOh, float* __restrict__ pM, float* __restrict__ pL) {
  __shared__ u16 Ksm[2][32 * 512];  // 2 x 32 KB
  __shared__ u16 Psm[64 * 40];      // 5 KB, row stride 80 B
  __shared__ float Alds[64];

  int bi = blockIdx.x;
  int b = bi & 7;
  int h = bi >> 8;
  int q8 = (bi >> 3) & 31;
  int qt = h ? (31 - q8) : q8;
  int c = h;
  int len = lens[b];
  int q0 = qt * 64;
  int kmax = min(q0 + 63, len - 1);
  int lastT = kmax >> 5;            // 32-key tiles (0..63)
  int half = qt + 1;                // chunk size at full length
  int t0 = c * half;
  int t1 = min(lastT + 1, t0 + half);
  int slot = (b * 32 + qt) * 2 + c;
  int tid = threadIdx.x;
  int w = tid >> 6, lane = tid & 63, la = lane & 15, hi = lane >> 4;

  if (t0 >= t1) {                   // empty chunk (short length)
    if (tid < 64) { pM[slot * 64 + tid] = -1e30f; pL[slot * 64 + tid] = 0.f; }
    return;
  }

  int r0 = q0 + w * 16;
  int qrow = r0 + la;               // q-row this lane owns in S^T domain

  // Q fragments (resident whole kernel)
  bf16x8 qf[16];
  const char* qbase = (const char*)Qb + (size_t)(b * NS + r0 + la) * ND * 2 + hi * 16;
#pragma unroll
  for (int kc = 0; kc < 16; ++kc) qf[kc] = *(const bf16x8*)(qbase + kc * 64);

  f32x4 o[4][8];                    // O[q = qb*16+hi*4+j][d = w*128+nb*16+la]
  f32x4 zero = {0.f, 0.f, 0.f, 0.f};
#pragma unroll
  for (int qb = 0; qb < 4; ++qb)
#pragma unroll
    for (int nb = 0; nb < 8; ++nb) o[qb][nb] = zero;
  float mrow = -1e30f, lrow = 0.f;

#define STAGE_K(T) {                                                            \
  _Pragma("unroll")                                                             \
  for (int i_ = 0; i_ < 8; ++i_) {                                              \
    int r_ = w * 8 + i_;                                                        \
    const char* g_ = (const char*)Kb + (size_t)(b * NS + (T) * 32 + r_) * ND * 2 \
                     + ((lane ^ (r_ & 7)) * 16);                                \
    GLD16(g_, (char*)Ksm[(T) & 1] + r_ * 1024);                                 \
  } }
#define LOAD_VF(T) {                                                            \
  const char* pan_ = (const char*)Vtb + ((size_t)(b * 64 + (T)) * 512) * 64;    \
  _Pragma("unroll")                                                             \
  for (int nb_ = 0; nb_ < 8; ++nb_) {                                           \
    int d_ = w * 128 + nb_ * 16 + la;                                           \
    vf[nb_] = *(const bf16x8*)(pan_ + d_ * 64 + hi * 16);                       \
  } }

  bf16x8 vf[8];
  STAGE_K(t0);
  LOAD_VF(t0);
  // retire qf + K(t0) for this wave (vf may still fly); then block-wide ready
  asm volatile("s_waitcnt vmcnt(8)" ::: "memory");
  __builtin_amdgcn_s_barrier();

  for (int t = t0; t < t1; ++t) {
    int k0 = t * 32;
    bool more = (t + 1 < t1);
    const char* kbase = (const char*)Ksm[t & 1];

    if (more) STAGE_K(t + 1);       // into buf^1: no conflict with QK(t) reads

    // QK^T (swapped): s[f] rows = keys f*16+hi*4+j, col = q-row la
    f32x4 s[2];
    s[0] = zero; s[1] = zero;
    __builtin_amdgcn_s_setprio(1);
#pragma unroll
    for (int kc = 0; kc < 16; ++kc) {
#pragma unroll
      for (int f = 0; f < 2; ++f) {
        int row = f * 16 + la;
        const char* p = kbase + row * 1024 + ((kc * 64 + hi * 16) ^ ((row & 7) * 16));
        bf16x8 kf = *(const bf16x8*)p;
        s[f] = mfma16(kf, qf[kc], s[f]);
      }
    }
    __builtin_amdgcn_s_setprio(0);

    // mask + online softmax (per q-row = lane la, replicated across hi)
    float tmax = -1e30f;
#pragma unroll
    for (int f = 0; f < 2; ++f) {
#pragma unroll
      for (int j = 0; j < 4; ++j) {
        int kabs = k0 + f * 16 + hi * 4 + j;
        bool ok = (kabs <= qrow) && (kabs < len);
        float vv = ok ? s[f][j] : -1e30f;
        s[f][j] = vv;
        tmax = fmaxf(tmax, vv);
      }
    }
    tmax = fmaxf(tmax, __shfl_xor(tmax, 16));
    tmax = fmaxf(tmax, __shfl_xor(tmax, 32));
    float mnew = fmaxf(fmaxf(mrow, tmax), -1e20f);  // floor: all-masked rows keep l=0
    float alpha = __expf(mrow - mnew);
    float psum = 0.f;
#pragma unroll
    for (int f = 0; f < 2; ++f) {
#pragma unroll
      for (int j = 0; j < 4; ++j) {
        float p = __expf(s[f][j] - mnew);
        s[f][j] = p;
        psum += p;
      }
    }
    psum += __shfl_xor(psum, 16);
    psum += __shfl_xor(psum, 32);
    lrow = lrow * alpha + psum;
    mrow = mnew;

    // publish P (bf16) + alpha
#pragma unroll
    for (int f = 0; f < 2; ++f) {
      u16x4 pk;
#pragma unroll
      for (int j = 0; j < 4; ++j) pk[j] = f2bf(s[f][j]);
      *(u16x4*)((char*)Psm + (w * 16 + la) * 80 + f * 32 + hi * 8) = pk;
    }
    if (hi == 0) Alds[w * 16 + la] = alpha;
    asm volatile("s_waitcnt lgkmcnt(0)" ::: "memory");
    // vf(t) must be landed for PV; K(t+1)'s 8 loads stay in flight
    if (more) { asm volatile("s_waitcnt vmcnt(8)" ::: "memory"); }
    else      { asm volatile("s_waitcnt vmcnt(0)" ::: "memory"); }
    __builtin_amdgcn_s_barrier();            // P/Alds visible

    // rescale O by alpha (per O-row q = qb*16+hi*4+j)
    float aq[4][4];
#pragma unroll
    for (int qb = 0; qb < 4; ++qb)
#pragma unroll
      for (int j = 0; j < 4; ++j) aq[qb][j] = Alds[qb * 16 + hi * 4 + j];
#pragma unroll
    for (int qb = 0; qb < 4; ++qb)
#pragma unroll
      for (int nb = 0; nb < 8; ++nb) {
        o[qb][nb][0] *= aq[qb][0]; o[qb][nb][1] *= aq[qb][1];
        o[qb][nb][2] *= aq[qb][2]; o[qb][nb][3] *= aq[qb][3];
      }

    // PV: wave owns d-slice w*128..+128; one MFMA per (qb,nb)
    __builtin_amdgcn_s_setprio(1);
#pragma unroll
    for (int qb = 0; qb < 4; ++qb) {
      bf16x8 pf = *(const bf16x8*)((const char*)Psm + (qb * 16 + la) * 80 + hi * 16);
#pragma unroll
      for (int nb = 0; nb < 8; ++nb) o[qb][nb] = mfma16(pf, vf[nb], o[qb][nb]);
    }
    __builtin_amdgcn_s_setprio(0);

    if (more) {
      LOAD_VF(t + 1);                                   // vf regs for t+1
      asm volatile("s_waitcnt vmcnt(8)" ::: "memory");  // K(t+1) landed (per wave)
      __builtin_amdgcn_s_barrier();                     // Ksm[buf^1] ready; Psm reads done
    }
  }

  // epilogue: bf16 partials + m/l
  if (hi == 0) { pM[slot * 64 + w * 16 + la] = mrow; pL[slot * 64 + w * 16 + la] = lrow; }
  u16* dst = pOh + (size_t)slot * (64 * 512);
#pragma unroll
  for (int qb = 0; qb < 4; ++qb)
#pragma unroll
    for (int nb = 0; nb < 8; ++nb) {
      int base = (qb * 16 + hi * 4) * 512 + w * 128 + nb * 16 + la;
#pragma unroll
      for (int j = 0; j < 4; ++j) dst[base + j * 512] = f2bf(o[qb][nb][j]);
    }
#undef STAGE_K
#undef LOAD_VF
}

// ---------------- combine the 2 chunks per (b, qt) --------------------------
__global__ __launch_bounds__(256) void combine_kernel(
    const u16* __restrict__ pOh, const float* __restrict__ pM,
    const float* __restrict__ pL, float* __restrict__ out) {
  int qt = blockIdx.x, b = blockIdx.y;
  int s0 = (b * 32 + qt) * 2;
  int tid = threadIdx.x;
  int row = tid >> 2, qq = tid & 3;   // row 0..63, d-quarter (128 each)
  float m0 = pM[s0 * 64 + row], m1 = pM[(s0 + 1) * 64 + row];
  float l0 = pL[s0 * 64 + row], l1 = pL[(s0 + 1) * 64 + row];
  float m = fmaxf(m0, m1);
  float a0 = __expf(m0 - m), a1 = __expf(m1 - m);
  float linv = 1.0f / (l0 * a0 + l1 * a1);   // l0 > 0 always (key 0 unmasked)
  float c0 = a0 * linv, c1 = a1 * linv;
  bool has1 = (l1 > 0.f);
  const uint4* O0 = (const uint4*)(pOh + (size_t)s0 * 32768) + row * 64 + qq * 16;
  const uint4* O1 = (const uint4*)(pOh + (size_t)(s0 + 1) * 32768) + row * 64 + qq * 16;
  float4* Op = (float4*)(out + ((size_t)b * NS + qt * 64 + row) * ND) + qq * 32;
#pragma unroll 4
  for (int k = 0; k < 16; ++k) {
    uint4 v0 = O0[k];
    uint4 v1 = has1 ? O1[k] : uint4{0, 0, 0, 0};
    u32 w0[4] = {v0.x, v0.y, v0.z, v0.w};
    u32 w1[4] = {v1.x, v1.y, v1.z, v1.w};
    float4 r[2];
#pragma unroll
    for (int p = 0; p < 4; ++p) {
      float f0lo = __uint_as_float(w0[p] << 16), f0hi = __uint_as_float(w0[p] & 0xFFFF0000u);
      float f1lo = __uint_as_float(w1[p] << 16), f1hi = __uint_as_float(w1[p] & 0xFFFF0000u);
      ((float*)r)[p * 2]     = f0lo * c0 + f1lo * c1;
      ((float*)r)[p * 2 + 1] = f0hi * c0 + f1hi * c1;
    }
    Op[k * 2] = r[0];
    Op[k * 2 + 1] = r[1];
  }
}

extern "C" void kernel_launch(void* const* d_in, const int* in_sizes, int n_in,
                              void* d_out, int out_size, void* d_ws, size_t ws_size,
                              hipStream_t stream) {
  const float* batch = (const float*)d_in[0];
  const float* wq = (const float*)d_in[1];
  const float* bq = (const float*)d_in[2];
  const float* wk = (const float*)d_in[3];
  const float* bk = (const float*)d_in[4];
  const float* wv = (const float*)d_in[5];
  const float* bv = (const float*)d_in[6];
  const int* lens = (const int*)d_in[7];

  char* ws = (char*)d_ws;
  // Q/K/Vtb live through attn. Xb/W* dead after gemm -> pOh aliases them.
  u16* Qb   = (u16*)(ws + 0);          // 16 MB
  u16* Kb   = (u16*)(ws + 16777216);   // 16 MB
  u16* Vtb  = (u16*)(ws + 33554432);   // 16 MB  [B][64][512][32] panels
  u16* Xb   = (u16*)(ws + 50331648);   // 16 MB  (dead after gemm)
  u16* Wqb  = (u16*)(ws + 67108864);   // 512 KB (dead after gemm)
  u16* Wkb  = (u16*)(ws + 67633152);   // 512 KB
  u16* Wvb  = (u16*)(ws + 68157440);   // 512 KB
  u16* pOh  = (u16*)(ws + 50331648);   // 32 MB: 512 slots x 64x512 bf16 (aliases Xb/W*)
  float* pM = (float*)(ws + 83886080);  // 128 KB
  float* pL = (float*)(ws + 84017152);  // 128 KB; total ws use ~84.1 MB

  cvt_kernel<<<dim3(2048), dim3(256), 0, stream>>>(batch, wq, wk, wv, Xb, Wqb, Wkb, Wvb);
  qkv_gemm<<<dim3(128, 4, 3), dim3(256), 0, stream>>>(Xb, Wqb, Wkb, Wvb, bq, bk, bv, Qb, Kb, Vtb);
  attn_kernel<<<dim3(512), dim3(256), 0, stream>>>(Qb, Kb, Vtb, lens, pOh, pM, pL);
  combine_kernel<<<dim3(32, 8), dim3(256), 0, stream>>>(pOh, pM, pL, (float*)d_out);
}